// Round 6
// baseline (306.407 us; speedup 1.0000x reference)
//
#include <hip/hip_runtime.h>
#include <math.h>

#define NEGV -1e30f

constexpr int Bc = 256;          // batch
constexpr int Tc = 256;          // time
constexpr int Cc = 512;          // classes (blank = Cc-1)
constexpr int Lc = 64;           // max label length
constexpr int EP = 68;           // emission row in LDS: [0]=blank, [1..64]=labels
constexpr float INVLN2 = 1.44269504088896340736f;
constexpr float LN2    = 0.69314718055994530942f;

// log2-domain logaddexp: log2(2^a + 2^b). Exact; NEGV-safe.
// exp2f lowers to v_exp_f32; -fabsf folds into the input modifier.
__device__ __forceinline__ float la2(float a, float b) {
    float m = fmaxf(a, b);
    float d = fabsf(a - b);
    return m + __log2f(exp2f(-d) + 1.0f);
}

// ---------------------------------------------------------------------------
// One block per batch element.
// Phase A (4 waves): emissions for all 256 timesteps -> LDS E[] (log2 domain).
//   wave w handles t = w + 4i; 2x float4/lane, depth-2 named-scalar prefetch.
// Phase B (wave 0): serial alpha recurrence, states in registers.
//   Lane l owns s=2l (blank) and s=2l+1 (label l); lane 63 also owns s=128
//   (lane-local: alpha[127] is its own ao). One shfl_up per timestep, and the
//   3-way lse is re-associated so only la2(.,po) sits after the shfl.
// ---------------------------------------------------------------------------
__global__ __launch_bounds__(256) void ctc_k(const float* __restrict__ logits,
                                             const int* __restrict__ labels,
                                             const int* __restrict__ lab_len,
                                             const int* __restrict__ log_len,
                                             float* __restrict__ nll) {
    const int b    = blockIdx.x;
    const int tid  = threadIdx.x;
    const int w    = tid >> 6;
    const int lane = tid & 63;

    __shared__ float E[Tc * EP];        // 69,632 B
    __shared__ float rows[4][Cc];       //  8,192 B

    const int mylab = labels[b * Lc + lane];

    // ---- Phase A ----
    const float4* rp = (const float4*)(logits + (size_t)b * Tc * Cc); // 128 f4/row
    float4 c0 = rp[w * 128 + lane],        c1 = rp[w * 128 + 64 + lane];
    float4 n0 = rp[(w + 4) * 128 + lane],  n1 = rp[(w + 4) * 128 + 64 + lane];

    for (int i = 0; i < Tc / 4; ++i) {
        const int t  = w + 4 * i;
        const int tn = (i + 2 < Tc / 4) ? t + 8 : t;     // clamped prefetch row
        float4 f0 = rp[tn * 128 + lane];
        float4 f1 = rp[tn * 128 + 64 + lane];

        ((float4*)rows[w])[lane]      = c0;
        ((float4*)rows[w])[lane + 64] = c1;

        float e = __expf(c0.x) + __expf(c0.y) + __expf(c0.z) + __expf(c0.w)
                + __expf(c1.x) + __expf(c1.y) + __expf(c1.z) + __expf(c1.w);
#pragma unroll
        for (int o = 32; o; o >>= 1) e += __shfl_xor(e, o, 64);
        float lse2 = __log2f(e);

        float xl = rows[w][mylab];                        // in-wave LDS gather
        E[t * EP + 1 + lane] = xl * INVLN2 - lse2;
        if (lane == 63) E[t * EP] = c1.w * INVLN2 - lse2; // class 511 = blank

        c0 = n0; c1 = n1; n0 = f0; n1 = f1;
    }
    __syncthreads();
    if (tid >= 64) return;

    // ---- Phase B ----
    const int l = lane;
    const int prevlab = __shfl_up(mylab, 1, 64);
    const bool skip   = (l >= 1) && (mylab != prevlab);
    const int  llm1   = log_len[b] - 1;

    float ae, ao, ax;                    // alpha2[2l], alpha2[2l+1], alpha2[128]
    float fe = NEGV, fo = NEGV, fx = NEGV;

    ae = (l == 0) ? E[0]     : NEGV;
    ao = (l == 0) ? E[1 + l] : NEGV;     // E[1] on lane 0
    ax = NEGV;
    if (llm1 == 0) { fe = ae; fo = ao; fx = ax; }

    float b1 = E[EP],     l1 = E[EP + 1 + l];         // t = 1
    float b2 = E[2 * EP], l2 = E[2 * EP + 1 + l];     // t = 2

#pragma unroll 2
    for (int t = 1; t < Tc; ++t) {
        const float em_b = b1, em_l = l1;
        b1 = b2; l1 = l2;
        const int tp = (t + 2 < Tc) ? t + 2 : Tc - 1;
        b2 = E[tp * EP];
        l2 = E[tp * EP + 1 + l];

        float q  = la2(ao, ae);          // pre-shfl work
        float x2 = la2(ax, ao);

        float po = __shfl_up(ao, 1, 64); // alpha2[2l-1]
        if (l == 0) po = NEGV;

        float nae = la2(ae, po) + em_b;                    // s = 2l
        float nao = (skip ? la2(q, po) : q) + em_l;        // s = 2l+1
        float nax = x2 + em_b;                             // s = 128 (lane 63)

        ae = nae; ao = nao; ax = nax;
        if (t == llm1) { fe = ae; fo = ao; fx = ax; }
    }

    const int L  = lab_len[b];
    float f0 = (L == 64) ? __shfl(fx, 63, 64) : __shfl(fe, L, 64);
    float f1 = __shfl(fo, L - 1, 64);
    float res = -LN2 * la2(f0, f1);
    if (l == 0) nll[b] = res;
}

// Single block: mean of the 256 per-batch NLLs.
__global__ __launch_bounds__(256) void reduce_k(const float* __restrict__ nll,
                                                float* __restrict__ out) {
    int tid = threadIdx.x;
    float v = nll[tid];
#pragma unroll
    for (int o = 32; o; o >>= 1) v += __shfl_xor(v, o, 64);
    __shared__ float pr[4];
    if ((tid & 63) == 0) pr[tid >> 6] = v;
    __syncthreads();
    if (tid == 0) out[0] = (pr[0] + pr[1] + pr[2] + pr[3]) * (1.0f / Bc);
}

extern "C" void kernel_launch(void* const* d_in, const int* in_sizes, int n_in,
                              void* d_out, int out_size, void* d_ws, size_t ws_size,
                              hipStream_t stream) {
    const float* logits  = (const float*)d_in[0];
    const int*   labels  = (const int*)d_in[1];
    const int*   lab_len = (const int*)d_in[2];
    const int*   log_len = (const int*)d_in[3];
    float* out = (float*)d_out;
    float* nll = (float*)d_ws;   // 256 floats

    hipLaunchKernelGGL(ctc_k, dim3(Bc), dim3(256), 0, stream,
                       logits, labels, lab_len, log_len, nll);
    hipLaunchKernelGGL(reduce_k, dim3(1), dim3(256), 0, stream, nll, out);
}